// Round 6
// baseline (105.987 us; speedup 1.0000x reference)
//
#include <hip/hip_runtime.h>
#include <hip/hip_bf16.h>

#define K 16
#define Bn 1024
#define Tn 512
#define START_ID 14
#define STOP_ID 15
#define LN2 0.69314718055994530942f
#define NCH 8          // chunks per sequence (one block = one sequence)
#define CL 64          // chunk length == wave size; threadIdx.x == t

typedef float f32x4 __attribute__((ext_vector_type(4)));
typedef short s16x4 __attribute__((ext_vector_type(4)));
typedef __bf16 bf16x4 __attribute__((ext_vector_type(4)));

// f32x4 -> bf16x4 as a single vector convert (2x v_cvt_pk_bf16_f32, RNE).
static __device__ __forceinline__ s16x4 pack4(f32x4 v) {
    union { bf16x4 b; s16x4 s; } u;
    u.b = __builtin_convertvector(v, bf16x4);
    return u.s;
}

// ---------------------------------------------------------------------------
// Chain structure identical to the validated R8/R10 kernel. One block
// (8 waves) per sequence; wave c evolves chunk c (64 steps) of the 16x16
// linear-space transfer matrix P <- (D_t E) P, one mfma/step, exp(h) folded
// into the A-operand; per-column pow2 rescale every 8 steps; gold fused;
// P/esum/gold -> LDS -> wave 0 combines -> fwd_b - gold_b.
//
// R6: crf_final fused via last-block-done, but with SCOPED ATOMICS instead
// of R3's __threadfence (which is a full per-block L2 writeback on this
// 8-XCD chip — the actual source of R3's +13us):
//   * res[b] published with an agent-scope atomic store (single sc-bit
//     store, cross-XCD visible, no L2 flush);
//   * lane0 does fetch_add(cnt, ACQ_REL, AGENT); the RMW release chain
//     gives the block seeing old==Bn-1 acquire over all published values;
//   * that block re-reads res[] with agent-scope loads (bypass stale L2)
//     and reduces 16/lane x 64 lanes -> out[0].
// cnt is memset (4B) per launch. Removes the crf_final dispatch + gap
// (~3-7us of an ~11-17us controllable region; fills are ~88us fixed).
// ---------------------------------------------------------------------------
__global__ __launch_bounds__(512, 8) void crf_all(
    const float* __restrict__ h, const int* __restrict__ y,
    const float* __restrict__ trans, float* __restrict__ res,
    unsigned* __restrict__ cnt, float* __restrict__ out)
{
    __shared__ float Pl[NCH][16][16];   // [chunk][row][col]
    __shared__ float El[NCH][16];       // per-column exponent sums
    __shared__ float Gl[NCH];           // per-wave gold partials

    int tid  = threadIdx.x;             // == t
    int lane = tid & 63;
    int c    = tid >> 6;                // wave id == chunk id
    int b    = blockIdx.x;
    int s = lane & 15, q = lane >> 4;

    const int* yseq = y + (size_t)b * Tn;
    int yt = yseq[tid];
    unsigned long long bal = __ballot(yt != 0);
    int nv = __popcll(bal);             // valid steps in this chunk (prefix)

    // ---- gold loads: issued early (pre-warms L2); reduce deferred ----
    const float* hseq = h + ((size_t)b * Tn) * K;
    int ytc = yt ? yt : 1;              // clamp so loads are unconditional
    int yp  = (tid == 0) ? START_ID : yseq[tid - 1];
    float g_h = hseq[(size_t)tid * K + ytc];
    float g_t = trans[ytc * K + yp];
    bool last = (tid == Tn - 1) || (yseq[tid + 1] == 0);
    float g_s = trans[STOP_ID * K + ytc];

    // ---- chain ----
    f32x4 E0v;
#pragma unroll
    for (int r = 0; r < 4; ++r)
        E0v[r] = __expf(trans[s * K + 4 * q + r]);   // exp(-10000) -> 0

    f32x4 P;
    s16x4 bfrag;
#pragma unroll
    for (int r = 0; r < 4; ++r) {
        P[r] = (4 * q + r == s) ? 1.0f : 0.0f;
        ((short*)&bfrag)[r] = (4 * q + r == s) ? (short)0x3F80 : (short)0;
    }

    int esum = 0, pend = 0;
    const float* hcs = hseq + (size_t)c * CL * K + s;

    float hcur[8], hnxt[8];
#pragma unroll
    for (int r = 0; r < 8; ++r) hcur[r] = hcs[(size_t)r * K];

    for (int sb = 0; sb < CL / 8; ++sb) {
        int base = sb * 8;
        if (base >= nv) break;                 // wave-uniform
        int n = nv - base; if (n > 8) n = 8;

        esum += pend;
        float sc = __uint_as_float((unsigned)(127 - pend) << 23); // exact 2^-pend
        pend = 0;
        P *= sc;                                // 2x v_pk_mul_f32
        bfrag = pack4(P);                       // 2x v_cvt_pk_bf16_f32

        float es[8];
#pragma unroll
        for (int r = 0; r < 8; ++r) es[r] = __expf(hcur[r]);
#pragma unroll
        for (int r = 0; r < 8; ++r) {          // depth-1 prefetch (clamped)
            int tt = base + 8 + r; tt = tt > CL - 1 ? CL - 1 : tt;
            hnxt[r] = hcs[(size_t)tt * K];
        }
#pragma unroll
        for (int r = 0; r < 8; ++r) {
            if (r >= n) break;                 // wave-uniform
            f32x4 av = E0v * es[r];            // 2x v_pk_mul_f32
            s16x4 afrag = pack4(av);           // 2x v_cvt_pk_bf16_f32
            f32x4 C = __builtin_amdgcn_mfma_f32_16x16x16bf16_1k(
                afrag, bfrag, (f32x4){0.f, 0.f, 0.f, 0.f}, 0, 0, 0);
            if (r == 3) {                      // per-column max -> pending 2^e
                float m4 = fmaxf(fmaxf(C[0], C[1]), fmaxf(C[2], C[3]));
                m4 = fmaxf(m4, __shfl_xor(m4, 16, 64));
                m4 = fmaxf(m4, __shfl_xor(m4, 32, 64));
                int e = (int)(__float_as_uint(m4) >> 23) - 127;
                pend = e < -126 ? -126 : (e > 126 ? 126 : e);
            }
            bfrag = pack4(C);                  // 2x v_cvt_pk_bf16_f32
            P = C;
        }
#pragma unroll
        for (int r = 0; r < 8; ++r) hcur[r] = hnxt[r];
    }

    // ---- deferred gold reduce (gather latency hidden under the chain) ----
    float g = (yt != 0) ? (g_h + g_t + (last ? g_s : 0.f)) : 0.f;
#pragma unroll
    for (int off = 32; off; off >>= 1) g += __shfl_xor(g, off, 64);
    if (lane == 0) Gl[c] = g;

    // publish chunk result (column s, rows 4q+r)
#pragma unroll
    for (int r = 0; r < 4; ++r)
        Pl[c][4 * q + r][s] = P[r];
    if (q == 0) El[c][s] = (float)esum;
    __syncthreads();

    // ---- combine (wave 0): alpha = e_START; alpha' = P~ * ldexp(w) ----
    if (c == 0) {
        int j = s;
        float ap[4];
#pragma unroll
        for (int r = 0; r < 4; ++r) ap[r] = (4 * q + r == START_ID) ? 1.0f : 0.0f;
        float ls = 0.f;

#pragma unroll
        for (int cc = 0; cc < NCH; ++cc) {
            f32x4 Pr  = *(const f32x4*)&Pl[cc][j][4 * q];
            f32x4 Erv = *(const f32x4*)&El[cc][4 * q];
            float me = fmaxf(fmaxf(Erv[0], Erv[1]), fmaxf(Erv[2], Erv[3]));
            me = fmaxf(me, __shfl_xor(me, 16, 64));
            me = fmaxf(me, __shfl_xor(me, 32, 64));
            float w0 = ldexpf(ap[0], (int)(Erv[0] - me));
            float w1 = ldexpf(ap[1], (int)(Erv[1] - me));
            float w2 = ldexpf(ap[2], (int)(Erv[2] - me));
            float w3 = ldexpf(ap[3], (int)(Erv[3] - me));
            float acc = Pr[0]*w0 + Pr[1]*w1 + Pr[2]*w2 + Pr[3]*w3;
            acc += __shfl_xor(acc, 16, 64);
            acc += __shfl_xor(acc, 32, 64);    // alpha'[j] at every lane
            float mj = acc;
#pragma unroll
            for (int off = 1; off < 16; off <<= 1)
                mj = fmaxf(mj, __shfl_xor(mj, off, 64));
            ls += me * LN2 + __logf(mj);
            float an = acc * (1.0f / mj);
#pragma unroll
            for (int r = 0; r < 4; ++r)
                ap[r] = __shfl(an, q * 4 + r, 16);
        }

        float part = 0.f;
#pragma unroll
        for (int r = 0; r < 4; ++r)
            part += ap[r] * __expf(trans[STOP_ID * K + 4 * q + r]);
        part += __shfl_xor(part, 16, 64);
        part += __shfl_xor(part, 32, 64);

        // ---- publish + last-block finalize (scoped atomics, no fences) ----
        unsigned old = 0;
        if (lane == 0) {
            float gold = Gl[0] + Gl[1] + Gl[2] + Gl[3]
                       + Gl[4] + Gl[5] + Gl[6] + Gl[7];
            float myres = ls + __logf(part) - gold;
            // agent-scope store: cross-XCD visible, no L2 flush
            __hip_atomic_store(&res[b], myres, __ATOMIC_RELAXED,
                               __HIP_MEMORY_SCOPE_AGENT);
            // release: orders the res store before the counter bump;
            // acquire: the winner synchronizes with the whole RMW chain
            old = __hip_atomic_fetch_add(cnt, 1u, __ATOMIC_ACQ_REL,
                                         __HIP_MEMORY_SCOPE_AGENT);
        }
        old = __shfl(old, 0, 64);
        if (old == Bn - 1) {                   // last block: reduce all 1024
            float v = 0.f;
#pragma unroll
            for (int k2 = 0; k2 < 16; ++k2)
                v += __hip_atomic_load(&res[lane + 64 * k2], __ATOMIC_RELAXED,
                                       __HIP_MEMORY_SCOPE_AGENT);
#pragma unroll
            for (int off = 32; off; off >>= 1) v += __shfl_xor(v, off, 64);
            if (lane == 0) out[0] = v * (1.0f / Bn);
        }
    }
}

extern "C" void kernel_launch(void* const* d_in, const int* in_sizes, int n_in,
                              void* d_out, int out_size, void* d_ws, size_t ws_size,
                              hipStream_t stream)
{
    const float* h     = (const float*)d_in[0];
    const int*   y     = (const int*)d_in[1];
    const float* trans = (const float*)d_in[3];
    float* out = (float*)d_out;
    float* res = (float*)d_ws;                          // 1024 floats
    unsigned* cnt = (unsigned*)((char*)d_ws + 4096);    // arrival counter

    hipMemsetAsync(cnt, 0, sizeof(unsigned), stream);   // graph-capturable
    crf_all<<<Bn, 512, 0, stream>>>(h, y, trans, res, cnt, out);
}

// Round 7
// 102.915 us; speedup vs baseline: 1.0298x; 1.0298x over previous
//
#include <hip/hip_runtime.h>
#include <hip/hip_bf16.h>

#define K 16
#define Bn 1024
#define Tn 512
#define START_ID 14
#define STOP_ID 15
#define LN2 0.69314718055994530942f
#define NCH 8          // chunks per sequence (one block = one sequence)
#define CL 64          // chunk length == wave size; threadIdx.x == t

typedef float f32x4 __attribute__((ext_vector_type(4)));
typedef short s16x4 __attribute__((ext_vector_type(4)));
typedef __bf16 bf16x4 __attribute__((ext_vector_type(4)));

// f32x4 -> bf16x4 as a single vector convert (2x v_cvt_pk_bf16_f32, RNE).
static __device__ __forceinline__ s16x4 pack4(f32x4 v) {
    union { bf16x4 b; s16x4 s; } u;
    u.b = __builtin_convertvector(v, bf16x4);
    return u.s;
}

// ---------------------------------------------------------------------------
// FINAL CONFIGURATION — exact revert to the best-measured variant (R2:
// 101.9 us; same structure as the 99.2 us baseline). Session ledger:
//  * VALU-thinning (cvt_pk pack, packed-f32): neutral x2 -> not VALU-bound.
//  * Last-block fusion: __threadfence variant +13us (per-block L2 writeback
//    x1024); scoped-atomic variant neutral -> crf_final dispatch is off the
//    critical path (graph-captured, launch-pipelined). Fusion dead end.
//  * Deferred-gold prologue (unconditional 3-load gather): consistent
//    ~+3.5us split (R5/R6 105.3/106.0 vs R0-R2 99.2-102.5) -> reverted;
//    conditional gold gather kept in the prologue.
//  * Combine without mj-normalization: NaN (unapplied pend residual
//    compounds across chunks) -> mj normalization is load-bearing.
// Counters: all pipes <25% (MfmaUtil 3%, VALUBusy 21%, HBM 2.7%), occupancy
// at the 2048-thread/CU cap -> latency-bound per-block critical path; the
// timed region is dominated by ~88us of harness re-poison fills already at
// 75-79% of HBM peak.
//
// Structure: one block (8 waves) per sequence; wave c evolves chunk c
// (64 steps) of the 16x16 linear-space transfer matrix P <- (D_t E) P, one
// mfma/step, exp(h) folded into the A-operand; per-column pow2 rescale every
// 8 steps (pend measured at r==3, applied at the next sub-block's B-pack);
// gold fused (1 gather/thread); P/esum/gold -> LDS -> wave 0 combines ->
// res[b] = fwd_b - gold_b; K2 reduces the 1024 partials.
// ---------------------------------------------------------------------------
__global__ __launch_bounds__(512, 8) void crf_all(
    const float* __restrict__ h, const int* __restrict__ y,
    const float* __restrict__ trans, float* __restrict__ res)
{
    __shared__ float Pl[NCH][16][16];   // [chunk][row][col]
    __shared__ float El[NCH][16];       // per-column exponent sums
    __shared__ float Gl[NCH];           // per-wave gold partials

    int tid  = threadIdx.x;             // == t
    int lane = tid & 63;
    int c    = tid >> 6;                // wave id == chunk id
    int b    = blockIdx.x;
    int s = lane & 15, q = lane >> 4;

    const int* yseq = y + (size_t)b * Tn;
    int yt = yseq[tid];
    unsigned long long bal = __ballot(yt != 0);
    int nv = __popcll(bal);             // valid steps in this chunk (prefix)

    // ---- gold: one (b,t) per thread; also pre-warms L2 ----
    const float* hseq = h + ((size_t)b * Tn) * K;
    float g = 0.f;
    if (yt != 0) {
        int yp = (tid == 0) ? START_ID : yseq[tid - 1];
        g = hseq[(size_t)tid * K + yt] + trans[yt * K + yp];
        bool last = (tid == Tn - 1) || (yseq[tid + 1] == 0);
        if (last) g += trans[STOP_ID * K + yt];
    }
#pragma unroll
    for (int off = 32; off; off >>= 1) g += __shfl_xor(g, off, 64);
    if (lane == 0) Gl[c] = g;

    // ---- chain ----
    f32x4 E0v;
#pragma unroll
    for (int r = 0; r < 4; ++r)
        E0v[r] = __expf(trans[s * K + 4 * q + r]);   // exp(-10000) -> 0

    f32x4 P;
    s16x4 bfrag;
#pragma unroll
    for (int r = 0; r < 4; ++r) {
        P[r] = (4 * q + r == s) ? 1.0f : 0.0f;
        ((short*)&bfrag)[r] = (4 * q + r == s) ? (short)0x3F80 : (short)0;
    }

    int esum = 0, pend = 0;
    const float* hcs = hseq + (size_t)c * CL * K + s;

    float hcur[8], hnxt[8];
#pragma unroll
    for (int r = 0; r < 8; ++r) hcur[r] = hcs[(size_t)r * K];

    for (int sb = 0; sb < CL / 8; ++sb) {
        int base = sb * 8;
        if (base >= nv) break;                 // wave-uniform
        int n = nv - base; if (n > 8) n = 8;

        esum += pend;
        float sc = __uint_as_float((unsigned)(127 - pend) << 23); // exact 2^-pend
        pend = 0;
        P *= sc;                                // 2x v_pk_mul_f32
        bfrag = pack4(P);                       // 2x v_cvt_pk_bf16_f32

        float es[8];
#pragma unroll
        for (int r = 0; r < 8; ++r) es[r] = __expf(hcur[r]);
#pragma unroll
        for (int r = 0; r < 8; ++r) {          // depth-1 prefetch (clamped)
            int tt = base + 8 + r; tt = tt > CL - 1 ? CL - 1 : tt;
            hnxt[r] = hcs[(size_t)tt * K];
        }
#pragma unroll
        for (int r = 0; r < 8; ++r) {
            if (r >= n) break;                 // wave-uniform
            f32x4 av = E0v * es[r];            // 2x v_pk_mul_f32
            s16x4 afrag = pack4(av);           // 2x v_cvt_pk_bf16_f32
            f32x4 C = __builtin_amdgcn_mfma_f32_16x16x16bf16_1k(
                afrag, bfrag, (f32x4){0.f, 0.f, 0.f, 0.f}, 0, 0, 0);
            if (r == 3) {                      // per-column max -> pending 2^e
                float m4 = fmaxf(fmaxf(C[0], C[1]), fmaxf(C[2], C[3]));
                m4 = fmaxf(m4, __shfl_xor(m4, 16, 64));
                m4 = fmaxf(m4, __shfl_xor(m4, 32, 64));
                int e = (int)(__float_as_uint(m4) >> 23) - 127;
                pend = e < -126 ? -126 : (e > 126 ? 126 : e);
            }
            bfrag = pack4(C);                  // 2x v_cvt_pk_bf16_f32
            P = C;
        }
#pragma unroll
        for (int r = 0; r < 8; ++r) hcur[r] = hnxt[r];
    }

    // publish chunk result (column s, rows 4q+r)
#pragma unroll
    for (int r = 0; r < 4; ++r)
        Pl[c][4 * q + r][s] = P[r];
    if (q == 0) El[c][s] = (float)esum;
    __syncthreads();

    // ---- combine (wave 0): alpha = e_START; alpha' = P~ * ldexp(w) ----
    if (c == 0) {
        int j = s;
        float ap[4];
#pragma unroll
        for (int r = 0; r < 4; ++r) ap[r] = (4 * q + r == START_ID) ? 1.0f : 0.0f;
        float ls = 0.f;

#pragma unroll
        for (int cc = 0; cc < NCH; ++cc) {
            f32x4 Pr  = *(const f32x4*)&Pl[cc][j][4 * q];
            f32x4 Erv = *(const f32x4*)&El[cc][4 * q];
            float me = fmaxf(fmaxf(Erv[0], Erv[1]), fmaxf(Erv[2], Erv[3]));
            me = fmaxf(me, __shfl_xor(me, 16, 64));
            me = fmaxf(me, __shfl_xor(me, 32, 64));
            float w0 = ldexpf(ap[0], (int)(Erv[0] - me));
            float w1 = ldexpf(ap[1], (int)(Erv[1] - me));
            float w2 = ldexpf(ap[2], (int)(Erv[2] - me));
            float w3 = ldexpf(ap[3], (int)(Erv[3] - me));
            float acc = Pr[0]*w0 + Pr[1]*w1 + Pr[2]*w2 + Pr[3]*w3;
            acc += __shfl_xor(acc, 16, 64);
            acc += __shfl_xor(acc, 32, 64);    // alpha'[j] at every lane
            float mj = acc;
#pragma unroll
            for (int off = 1; off < 16; off <<= 1)
                mj = fmaxf(mj, __shfl_xor(mj, off, 64));
            ls += me * LN2 + __logf(mj);
            float an = acc * (1.0f / mj);
#pragma unroll
            for (int r = 0; r < 4; ++r)
                ap[r] = __shfl(an, q * 4 + r, 16);
        }

        float part = 0.f;
#pragma unroll
        for (int r = 0; r < 4; ++r)
            part += ap[r] * __expf(trans[STOP_ID * K + 4 * q + r]);
        part += __shfl_xor(part, 16, 64);
        part += __shfl_xor(part, 32, 64);
        if (lane == 0) {
            float gold = Gl[0] + Gl[1] + Gl[2] + Gl[3]
                       + Gl[4] + Gl[5] + Gl[6] + Gl[7];
            res[b] = ls + __logf(part) - gold;
        }
    }
}

// ---------------------------------------------------------------------------
// K2: one block reduces 1024 per-sequence (fwd - gold) values, publishes mean.
// ---------------------------------------------------------------------------
__global__ __launch_bounds__(256) void crf_final(
    const float* __restrict__ res, float* __restrict__ out)
{
    int t = threadIdx.x;
    float v = 0.f;
#pragma unroll
    for (int k2 = 0; k2 < 4; ++k2) v += res[t + 256 * k2];
#pragma unroll
    for (int off = 32; off; off >>= 1) v += __shfl_xor(v, off, 64);
    __shared__ float red[4];
    if ((t & 63) == 0) red[t >> 6] = v;
    __syncthreads();
    if (t == 0) out[0] = (red[0] + red[1] + red[2] + red[3]) * (1.0f / Bn);
}

extern "C" void kernel_launch(void* const* d_in, const int* in_sizes, int n_in,
                              void* d_out, int out_size, void* d_ws, size_t ws_size,
                              hipStream_t stream)
{
    const float* h     = (const float*)d_in[0];
    const int*   y     = (const int*)d_in[1];
    const float* trans = (const float*)d_in[3];
    float* out = (float*)d_out;
    float* res = (float*)d_ws;          // 1024 floats

    crf_all<<<Bn, 512, 0, stream>>>(h, y, trans, res);
    crf_final<<<1, 256, 0, stream>>>(res, out);
}